// Round 13
// baseline (559.524 us; speedup 1.0000x reference)
//
#include <hip/hip_runtime.h>

typedef unsigned short u16;
typedef __attribute__((ext_vector_type(8))) short bf16x8;
typedef __attribute__((ext_vector_type(4))) float f32x4;
#define BATCH 16384

__device__ __forceinline__ float b2f(u16 u){ unsigned int i=((unsigned int)u)<<16; float f; __builtin_memcpy(&f,&i,4); return f; }
__device__ __forceinline__ u16 f2b(float f){ unsigned int x; __builtin_memcpy(&x,&f,4); unsigned int r=(x + 0x7fffu + ((x>>16)&1u))>>16; return (u16)r; }

// ---------------- prep: zero stats+gram + catb + transpose weights + gather ----------------
__global__ __launch_bounds__(256) void prep_kernel(float* __restrict__ S,
                                                   const float* __restrict__ hb0, const float* __restrict__ mb0,
                                                   float* __restrict__ catb,
                                                   const float* __restrict__ w0, const float* __restrict__ w1,
                                                   const float* __restrict__ w2, const float* __restrict__ w3,
                                                   const float* __restrict__ w4, const float* __restrict__ w5,
                                                   const float* __restrict__ w6,
                                                   u16* __restrict__ catWt, u16* __restrict__ t1,
                                                   u16* __restrict__ t2, u16* __restrict__ t4,
                                                   u16* __restrict__ t5, u16* __restrict__ t6,
                                                   const int* __restrict__ ids,
                                                   const float* __restrict__ emb,
                                                   u16* __restrict__ e){
  int blk = blockIdx.x;
  int tid = threadIdx.x;
  if (blk < 34){
    int i = blk*256 + tid;
    if (i < 8640) S[i] = 0.f;
  } else if (blk == 34){
    for (int i = tid; i < 640; i += 256) catb[i] = (i < 128) ? hb0[i] : mb0[i-128];
  } else if (blk < 1539){
    int c = blk - 35;
    if (c < 640){        int idx=c*256+tid;        int n=idx>>8, k=idx&255;
                         catWt[idx] = f2b(n<128 ? w0[k*128+n] : w3[k*512+(n-128)]); }
    else if (c < 672){   int idx=(c-640)*256+tid;  t1[idx]=f2b(w1[(idx%128)*64   + idx/128]); }
    else if (c < 928){   int idx=(c-672)*256+tid;  t2[idx]=f2b(w2[(idx%64)*1024  + idx/64]);  }
    else if (c < 1440){  int idx=(c-928)*256+tid;  t4[idx]=f2b(w4[(idx%512)*256  + idx/512]); }
    else if (c < 1472){  int idx=(c-1440)*256+tid; t5[idx]=f2b(w5[(idx%256)*32   + idx/256]); }
    else {               int idx=(c-1472)*256+tid; t6[idx]=f2b(w6[(idx%32)*256   + idx/32]);  }
  } else {
    int g = blk - 1539;
    int b = g*16 + (tid >> 4), f = tid & 15;
    int id = ids[b*16 + f];
    const float4* src = (const float4*)(emb + ((size_t)f*100000 + (size_t)id)*16);
    float4 v0 = src[0], v1 = src[1], v2 = src[2], v3 = src[3];
    u16 o[16] = { f2b(v0.x),f2b(v0.y),f2b(v0.z),f2b(v0.w), f2b(v1.x),f2b(v1.y),f2b(v1.z),f2b(v1.w),
                  f2b(v2.x),f2b(v2.y),f2b(v2.z),f2b(v2.w), f2b(v3.x),f2b(v3.y),f2b(v3.z),f2b(v3.w) };
    uint4 p0, p1; __builtin_memcpy(&p0, &o[0], 16); __builtin_memcpy(&p1, &o[8], 16);
    uint4* dst = (uint4*)(e + (size_t)b*256 + f*16);
    dst[0] = p0; dst[1] = p1;
  }
}

// ================= 64x64 MFMA GEMM, templated BK, register-prefetch pipeline =============
template<int BK>
__global__ __launch_bounds__(256) void gemm_mfma(const u16* __restrict__ A,
                                                 const u16* __restrict__ Wt,
                                                 const float* __restrict__ bias,
                                                 u16* __restrict__ Ca,
                                                 u16* __restrict__ Cb,
                                                 int Nsplit,
                                                 const float* __restrict__ asums,
                                                 const float* __restrict__ asumsq,
                                                 const float* __restrict__ ag,
                                                 const float* __restrict__ abe,
                                                 float* __restrict__ sums,
                                                 float* __restrict__ sumsq,
                                                 int N, int K){
  constexpr int STR = BK + 8;
  constexpr int EPT = BK/4;
  __shared__ u16 lds[64*STR*2];
  __shared__ float bnS[512], bnB[512];
  u16* As = lds;
  u16* Bs = lds + 64*STR;
  int tid = threadIdx.x;
  int n0 = blockIdx.x*64, m0 = blockIdx.y*64;
  int lane = tid & 63, w = tid >> 6, quad = lane >> 4, m16 = lane & 15;
  int srow = tid >> 2, skoff = (tid & 3)*EPT;
  if (asums != nullptr){
    for (int k = tid; k < K; k += 256){
      float mean = asums[k] * (1.f/(float)BATCH);
      float var  = asumsq[k] * (1.f/(float)BATCH) - mean*mean;
      float sc   = ag[k] * rsqrtf(var + 1e-5f);
      bnS[k] = sc;
      bnB[k] = abe[k] - mean*sc;
    }
    __syncthreads();
  }
  f32x4 acc[4] = {};
  int ng = n0 + srow;
  uint4 a0, a1, b0, b1;
  {
    const u16* ap = A + (size_t)(m0+srow)*K + skoff;
    a0 = *(const uint4*)ap;
    if (EPT == 16) a1 = *(const uint4*)(ap + 8);
    if (ng < N){
      const u16* bp = Wt + (size_t)ng*K + skoff;
      b0 = *(const uint4*)bp;
      if (EPT == 16) b1 = *(const uint4*)(bp + 8);
    } else { b0 = make_uint4(0u,0u,0u,0u); b1 = b0; }
  }
  for (int k0 = 0; k0 < K; k0 += BK){
    u16 at[EPT];
    __builtin_memcpy(at, &a0, 16);
    if (EPT == 16) __builtin_memcpy(at+8, &a1, 16);
    if (asums != nullptr){
#pragma unroll
      for (int j=0;j<EPT;j++){
        float v = b2f(at[j]) * bnS[k0+skoff+j] + bnB[k0+skoff+j];
        at[j] = f2b(v > 0.f ? v : 0.f);
      }
    }
    uint4 s0, s1;
    __builtin_memcpy(&s0, at, 16);
    *(uint4*)&As[srow*STR + skoff] = s0;
    if (EPT == 16){ __builtin_memcpy(&s1, at+8, 16); *(uint4*)&As[srow*STR + skoff + 8] = s1; }
    *(uint4*)&Bs[srow*STR + skoff] = b0;
    if (EPT == 16) *(uint4*)&Bs[srow*STR + skoff + 8] = b1;
    if (k0 + BK < K){
      const u16* ap = A + (size_t)(m0+srow)*K + k0 + BK + skoff;
      a0 = *(const uint4*)ap;
      if (EPT == 16) a1 = *(const uint4*)(ap + 8);
      if (ng < N){
        const u16* bp = Wt + (size_t)ng*K + k0 + BK + skoff;
        b0 = *(const uint4*)bp;
        if (EPT == 16) b1 = *(const uint4*)(bp + 8);
      }
    }
    __syncthreads();
#pragma unroll
    for (int sub=0; sub<BK/32; sub++){
      bf16x8 bfrag = *(bf16x8*)&Bs[(w*16 + m16)*STR + sub*32 + quad*8];
#pragma unroll
      for (int mc=0;mc<4;mc++){
        bf16x8 afrag = *(bf16x8*)&As[(mc*16 + m16)*STR + sub*32 + quad*8];
        acc[mc] = __builtin_amdgcn_mfma_f32_16x16x32_bf16(afrag, bfrag, acc[mc], 0, 0, 0);
      }
    }
    __syncthreads();
  }
  int cw = n0 + w*16 + m16;
  float bvv = (bias != nullptr && cw < N) ? bias[cw] : 0.f;
  float cs = 0.f, cq = 0.f;
  u16* Cs = lds;
#pragma unroll
  for (int mc=0;mc<4;mc++)
#pragma unroll
    for (int r=0;r<4;r++){
      float v = acc[mc][r] + bvv;
      cs += v; cq += v*v;
      Cs[(mc*16 + quad*4 + r)*72 + w*16 + m16] = f2b(v);
    }
  if (sums != nullptr){
    cs += __shfl_xor(cs, 16, 64); cs += __shfl_xor(cs, 32, 64);
    cq += __shfl_xor(cq, 16, 64); cq += __shfl_xor(cq, 32, 64);
    if (quad == 0 && cw < N){ atomicAdd(&sums[cw], cs); atomicAdd(&sumsq[cw], cq); }
  }
  __syncthreads();
  int row = tid >> 2, c4 = (tid & 3)*16;
  int cg = n0 + c4;
  if (cg < N){
    u16* outp; int stride, colbase;
    if (Cb != nullptr && n0 >= Nsplit){ outp = Cb; stride = N - Nsplit; colbase = cg - Nsplit; }
    else if (Cb != nullptr){            outp = Ca; stride = Nsplit;     colbase = cg; }
    else {                              outp = Ca; stride = N;          colbase = cg; }
    uint4 p0 = *(uint4*)&Cs[row*72 + c4];
    uint4 p1 = *(uint4*)&Cs[row*72 + c4 + 8];
    *(uint4*)(outp + (size_t)(m0+row)*stride + colbase) = p0;
    *(uint4*)(outp + (size_t)(m0+row)*stride + colbase + 8) = p1;
  }
}

// ---------------- gram: Y1' = relu(bn(Y1)); accumulate colsum[64] and G = Y1'^T Y1' -------
__global__ __launch_bounds__(256) void gram_kernel(const u16* __restrict__ Y1,
                                                   const float* __restrict__ ysums,
                                                   const float* __restrict__ ysumsq,
                                                   const float* __restrict__ yg,
                                                   const float* __restrict__ ybe,
                                                   u16* __restrict__ Y1p,
                                                   float* __restrict__ gsum,
                                                   float* __restrict__ G){
  __shared__ u16 As[64*72];
  __shared__ float bnSy[64], bnBy[64];
  int tid = threadIdx.x;
  int row0 = blockIdx.x*64;
  if (tid < 64){
    float mean = ysums[tid] * (1.f/(float)BATCH);
    float var  = ysumsq[tid] * (1.f/(float)BATCH) - mean*mean;
    float sc   = yg[tid] * rsqrtf(var + 1e-5f);
    bnSy[tid] = sc; bnBy[tid] = ybe[tid] - mean*sc;
  }
  __syncthreads();
  {
    int r = tid >> 2, c0 = (tid & 3)*16;
    const u16* src = Y1 + (size_t)(row0 + r)*64 + c0;
    uint4 v0 = *(const uint4*)src;
    uint4 v1 = *(const uint4*)(src + 8);
    u16 t[16]; __builtin_memcpy(t, &v0, 16); __builtin_memcpy(t+8, &v1, 16);
#pragma unroll
    for (int q=0;q<16;q++){
      float v = b2f(t[q]) * bnSy[c0+q] + bnBy[c0+q];
      t[q] = f2b(v > 0.f ? v : 0.f);
    }
    uint4 s0, s1; __builtin_memcpy(&s0, t, 16); __builtin_memcpy(&s1, t+8, 16);
    *(uint4*)&As[r*72 + c0] = s0;
    *(uint4*)&As[r*72 + c0 + 8] = s1;
    u16* dst = Y1p + (size_t)(row0 + r)*64 + c0;
    *(uint4*)dst = s0;
    *(uint4*)(dst + 8) = s1;
  }
  __syncthreads();
  if (tid < 64){
    float s = 0.f;
    for (int r = 0; r < 64; r++) s += b2f(As[r*72 + tid]);
    atomicAdd(&gsum[tid], s);
  }
  {
    int i = tid >> 2, j0 = (tid & 3)*16;
    float acc[16] = {};
    for (int r = 0; r < 64; r++){
      float ai = b2f(As[r*72 + i]);
#pragma unroll
      for (int jj=0;jj<16;jj++) acc[jj] += ai * b2f(As[r*72 + j0 + jj]);
    }
#pragma unroll
    for (int jj=0;jj<16;jj++) atomicAdd(&G[i*64 + j0 + jj], acc[jj]);
  }
}

// ---------------- hstats: H batch stats in closed form from colsum + Gram ----------------
__global__ __launch_bounds__(256) void hstats_kernel(const float* __restrict__ gsum,
                                                     const float* __restrict__ G,
                                                     const u16* __restrict__ hW2t,  // [1024][64]
                                                     const float* __restrict__ hb2,
                                                     float* __restrict__ hsums,
                                                     float* __restrict__ hsumsq){
  __shared__ float Gs[4096];
  __shared__ float gs[64];
  int tid = threadIdx.x;
  for (int k = tid; k < 4096; k += 256) Gs[k] = G[k];
  if (tid < 64) gs[tid] = gsum[tid];
  __syncthreads();
  int c = blockIdx.x*256 + tid;
  float w[64];
#pragma unroll
  for (int k8 = 0; k8 < 64; k8 += 8){
    uint4 v = *(const uint4*)(hW2t + (size_t)c*64 + k8);
    u16 t[8]; __builtin_memcpy(t, &v, 16);
#pragma unroll
    for (int q=0;q<8;q++) w[k8+q] = b2f(t[q]);
  }
  float s1 = 0.f;
#pragma unroll
  for (int k=0;k<64;k++) s1 += gs[k]*w[k];
  float q = 0.f;
  for (int i=0;i<64;i++){
    float t = 0.f;
#pragma unroll
    for (int j=0;j<64;j++) t += Gs[i*64+j]*w[j];
    q += w[i]*t;
  }
  float beta = hb2[c];
  hsums[c]  = s1 + (float)BATCH*beta;
  hsumsq[c] = q + 2.f*beta*s1 + (float)BATCH*beta*beta;
}

// ---------------- adapter core: H tile recomputed in-LDS via MFMA from Y1' ---------------
#define HSTR 1056
__global__ __launch_bounds__(512) void adapter_core(const u16* __restrict__ Y1p,
                                                    const u16* __restrict__ Mout,
                                                    const u16* __restrict__ u0t,
                                                    const u16* __restrict__ hW2t,  // [1024][64]
                                                    const float* __restrict__ hb2,
                                                    const float* __restrict__ v0,
                                                    const float* __restrict__ u1,
                                                    const float* __restrict__ ab0,
                                                    const float* __restrict__ hsums,
                                                    const float* __restrict__ hsumsq,
                                                    const float* __restrict__ hg,
                                                    const float* __restrict__ hbe,
                                                    const float* __restrict__ msums,
                                                    const float* __restrict__ msumsq,
                                                    const float* __restrict__ mg,
                                                    const float* __restrict__ mbe,
                                                    u16* __restrict__ Z2){
  __shared__ __align__(16) u16 Hs[16*HSTR];      // 33 KB
  __shared__ __align__(16) u16 Y1s[16*72];       // 2.3 KB
  __shared__ float bnS[1024], bnB2[1024];        // 8 KB (bias folded into bnB2)
  __shared__ __align__(8) u16 v0s[1024], u1s[1024];
  __shared__ float mS[256], mB[256];
  __shared__ __align__(16) u16 aS[16*256];
  __shared__ float Ps[512], qs[512], t1s[512], ss[512];
  __shared__ float ab0s[32];
  int tid = threadIdx.x;
  int r = tid >> 5, j = tid & 31;
  int lane = tid & 63, wv = tid >> 6, quad = lane >> 4, m16 = lane & 15;
  size_t row0 = (size_t)blockIdx.x * 16;

  // phase A: tables + raw staging
  for (int k = tid; k < 1024; k += 512){
    float mean = hsums[k] * (1.f/(float)BATCH);
    float var  = hsumsq[k] * (1.f/(float)BATCH) - mean*mean;
    float sc   = hg[k] * rsqrtf(var + 1e-5f);
    bnS[k] = sc; bnB2[k] = hbe[k] - mean*sc + sc*hb2[k];
  }
  if (tid < 256){
    float4 a = *(const float4*)(v0 + tid*4);
    ushort4 pa = { f2b(a.x), f2b(a.y), f2b(a.z), f2b(a.w) };
    *(ushort4*)&v0s[tid*4] = pa;
    float4 b4 = *(const float4*)(u1 + tid*4);
    ushort4 pb = { f2b(b4.x), f2b(b4.y), f2b(b4.z), f2b(b4.w) };
    *(ushort4*)&u1s[tid*4] = pb;
  } else {
    int c = tid - 256;
    float mean = msums[c] * (1.f/(float)BATCH);
    float var  = msumsq[c] * (1.f/(float)BATCH) - mean*mean;
    float sc   = mg[c] * rsqrtf(var + 1e-5f);
    mS[c] = sc; mB[c] = mbe[c] - mean*sc;
  }
  if (tid < 128){            // stage Y1' tile: 16 rows x 64
    int el = tid*8, rr = el >> 6, col = el & 63;
    uint4 v = *(const uint4*)(Y1p + row0*64 + el);
    *(uint4*)&Y1s[rr*72 + col] = v;
  }
  {                          // stage raw Mout rows
    int el = tid*8;
    uint4 mv = *(const uint4*)(Mout + row0*256 + el);
    *(uint4*)&aS[el] = mv;
  }
  if (tid < 32) ab0s[tid] = ab0[tid];
  __syncthreads();

  // phase B: aS = relu(bn(aS)); Hs = relu(bn(Y1s @ hW2^T + hb2)) via MFMA
  {
    int el = tid*8, col = el & 255;
    u16 mt[8]; __builtin_memcpy(mt, &aS[el], 16);
#pragma unroll
    for (int q=0;q<8;q++){
      float v = b2f(mt[q]) * mS[col+q] + mB[col+q];
      mt[q] = f2b(v > 0.f ? v : 0.f);
    }
    uint4 so; __builtin_memcpy(&so, mt, 16);
    *(uint4*)&aS[el] = so;
  }
  {
    bf16x8 af0 = *(bf16x8*)&Y1s[m16*72 + quad*8];
    bf16x8 af1 = *(bf16x8*)&Y1s[m16*72 + 32 + quad*8];
#pragma unroll
    for (int i=0;i<8;i++){
      int nt = wv*8 + i;
      const u16* bp = hW2t + (size_t)(nt*16 + m16)*64;
      bf16x8 bf0 = *(bf16x8*)(bp + quad*8);
      bf16x8 bf1 = *(bf16x8*)(bp + 32 + quad*8);
      f32x4 acc = {};
      acc = __builtin_amdgcn_mfma_f32_16x16x32_bf16(af0, bf0, acc, 0, 0, 0);
      acc = __builtin_amdgcn_mfma_f32_16x16x32_bf16(af1, bf1, acc, 0, 0, 0);
      int c = nt*16 + m16;
      float s = bnS[c], b = bnB2[c];
#pragma unroll
      for (int rr=0;rr<4;rr++){
        float v = acc[rr]*s + b;
        Hs[(quad*4+rr)*HSTR + c] = f2b(v > 0.f ? v : 0.f);
      }
    }
  }
  __syncthreads();

  // phase C: P[r][j] = sum_k aS[r][k] * u0t[j][k]
  {
    float acc = 0.f;
    for (int k8 = 0; k8 < 256; k8 += 8){
      uint4 vu = *(const uint4*)(u0t + j*256 + k8);
      uint4 va; __builtin_memcpy(&va, &aS[r*256 + k8], 16);
      u16 ta[8], tu[8]; __builtin_memcpy(ta, &va, 16); __builtin_memcpy(tu, &vu, 16);
#pragma unroll
      for (int q=0;q<8;q++) acc += b2f(ta[q]) * b2f(tu[q]);
    }
    Ps[tid] = acc;
  }
  __syncthreads();

  float acc = 0.f;
#pragma unroll
  for (int i=0;i<32;i++) acc += Ps[r*32+i] * b2f(Hs[r*HSTR + i*32 + j]);
  qs[tid] = acc;
  __syncthreads();
  acc = ab0s[j];
#pragma unroll
  for (int i=0;i<32;i++) acc += qs[r*32+i] * b2f(v0s[i*32+j]);
  t1s[tid] = 1.f / (1.f + __expf(-acc));
  __syncthreads();
  acc = 0.f;
#pragma unroll
  for (int i=0;i<32;i++) acc += t1s[r*32+i] * b2f(u1s[i*32+j]);
  ss[tid] = acc;
  __syncthreads();
  acc = 0.f;
#pragma unroll
  for (int i=0;i<32;i++) acc += ss[r*32+i] * b2f(Hs[r*HSTR + i*32 + j]);
  Z2[(row0 + r)*32 + j] = f2b(acc);
}

// ---------------- final head ----------------
__global__ __launch_bounds__(256) void final_kernel(const u16* __restrict__ e,
                                                    const float* __restrict__ cw,
                                                    const float* __restrict__ cb,
                                                    const u16* __restrict__ t,
                                                    const u16* __restrict__ mo,
                                                    const float* __restrict__ tsums,
                                                    const float* __restrict__ tsumsq,
                                                    const float* __restrict__ tg,
                                                    const float* __restrict__ tbe,
                                                    const float* __restrict__ msums,
                                                    const float* __restrict__ msumsq,
                                                    const float* __restrict__ mg,
                                                    const float* __restrict__ mbe,
                                                    const float* __restrict__ lw,
                                                    const float* __restrict__ lb,
                                                    float* __restrict__ out){
  __shared__ float tS[256], tB[256], mS[256], mB[256];
  int tid = threadIdx.x;
  {
    int c = tid;
    float mean = tsums[c] * (1.f/(float)BATCH);
    float var  = (tsumsq[c] - mean*mean*(float)BATCH) * (1.f/(float)(BATCH-1));
    float sc   = tg[c] * rsqrtf(var + 1e-5f);
    tS[c] = sc; tB[c] = tbe[c] - mean*sc;
    float mmean = msums[c] * (1.f/(float)BATCH);
    float mvar  = msumsq[c] * (1.f/(float)BATCH) - mmean*mmean;
    float msc   = mg[c] * rsqrtf(mvar + 1e-5f);
    mS[c] = msc; mB[c] = mbe[c] - mmean*msc;
  }
  __syncthreads();
  int wave = tid >> 6, lane = tid & 63;
  int b = blockIdx.x*4 + wave;
  int n4 = lane*4;
  ushort4 ev = *(const ushort4*)(e + (size_t)b*256 + n4);
  float ec[4] = { b2f(ev.x), b2f(ev.y), b2f(ev.z), b2f(ev.w) };
  float x[4]  = { ec[0], ec[1], ec[2], ec[3] };
  for (int i=0;i<3;i++){
    float p = 0.f;
#pragma unroll
    for (int q=0;q<4;q++) p += x[q] * cw[i*256 + n4 + q];
#pragma unroll
    for (int o=1;o<64;o<<=1) p += __shfl_xor(p, o, 64);
#pragma unroll
    for (int q=0;q<4;q++) x[q] = ec[q]*p + cb[i*256 + n4 + q] + x[q];
  }
  ushort4 tv = *(const ushort4*)(t  + (size_t)b*256 + n4);
  ushort4 mv = *(const ushort4*)(mo + (size_t)b*256 + n4);
  float ta[4] = { b2f(tv.x), b2f(tv.y), b2f(tv.z), b2f(tv.w) };
  float ma[4] = { b2f(mv.x), b2f(mv.y), b2f(mv.z), b2f(mv.w) };
  float p = 0.f;
#pragma unroll
  for (int q=0;q<4;q++){
    int n = n4 + q;
    p += x[q] * lw[n];
    float mr = ma[q]*mS[n] + mB[n];
    mr = mr > 0.f ? mr : 0.f;
    float mf = tS[n]*ta[q] + tB[n] + mr;
    p += mf * lw[256 + n];
  }
#pragma unroll
  for (int o=32;o>0;o>>=1) p += __shfl_down(p, o, 64);
  if (lane == 0){
    float y = p + lb[0];
    out[b] = 1.f / (1.f + __expf(-y));
  }
}

extern "C" void kernel_launch(void* const* d_in, const int* in_sizes, int n_in,
                              void* d_out, int out_size, void* d_ws, size_t ws_size,
                              hipStream_t stream) {
  const int B = BATCH;
  const int*   feat = (const int*)d_in[0];
  const float* emb  = (const float*)d_in[2];
  const float* hW0 = (const float*)d_in[3],  *hb0 = (const float*)d_in[4],  *hg0 = (const float*)d_in[5],  *hbe0 = (const float*)d_in[6];
  const float* hW1 = (const float*)d_in[7],  *hb1 = (const float*)d_in[8],  *hg1 = (const float*)d_in[9],  *hbe1 = (const float*)d_in[10];
  const float* hW2 = (const float*)d_in[11], *hb2 = (const float*)d_in[12], *hg2 = (const float*)d_in[13], *hbe2 = (const float*)d_in[14];
  const float* cw  = (const float*)d_in[15], *cb  = (const float*)d_in[16];
  const float* mW0 = (const float*)d_in[17], *mb0 = (const float*)d_in[18], *mg0 = (const float*)d_in[19], *mbe0 = (const float*)d_in[20];
  const float* mW1 = (const float*)d_in[21], *mb1 = (const float*)d_in[22], *mg1 = (const float*)d_in[23], *mbe1 = (const float*)d_in[24];
  const float* u0  = (const float*)d_in[25], *u1  = (const float*)d_in[26];
  const float* v0  = (const float*)d_in[27], *v1  = (const float*)d_in[28];
  const float* ab0 = (const float*)d_in[29], *ab1 = (const float*)d_in[30];
  const float* gamma1 = (const float*)d_in[31], *bias1 = (const float*)d_in[32];
  const float* lw  = (const float*)d_in[33], *lb = (const float*)d_in[34];
  float* out = (float*)d_out;

  // ---- workspace layout ----
  char* base = (char*)d_ws;
  const size_t MB = 1024*1024;
  u16* Y1p  = (u16*)(base);             // [B,64] activated Y1 (old H region)
  u16* e    = (u16*)(base + 32*MB);     // [B,256]
  u16* Y0   = (u16*)(base + 40*MB);     // [B,128]
  u16* Y1   = (u16*)(base + 44*MB);     // [B,64]
  u16* M0   = (u16*)(base + 48*MB);     // [B,512]
  u16* Mout = (u16*)(base + 64*MB);     // [B,256]
  u16* T    = (u16*)(base + 72*MB);     // [B,256]
  u16* Z2   = (u16*)(base + 80*MB);     // [B,32]
  u16* catWt= (u16*)(base + 88*MB);     // [640][256]
  u16* hW1t = catWt + 163840;           // [64][128]
  u16* hW2t = hW1t + 8192;              // [1024][64]
  u16* mW1t = hW2t + 65536;             // [256][512]
  u16* u0t  = mW1t + 131072;            // [32][256]
  u16* v1t  = u0t + 8192;               // [256][32]
  float* catb = (float*)(v1t + 8192);   // [640]
  float* S    = catb + 640;             // stats: 4480 | gsum 64 @4480 | G 4096 @4544
  float* gsum = S + 4480;
  float* G    = S + 4544;

  // 1. prep (zeroes S..G, builds catb, transposes weights, gathers e)
  prep_kernel<<<2563, 256, 0, stream>>>(S, hb0, mb0, catb,
                                        hW0, hW1, hW2, mW0, mW1, u0, v1,
                                        catWt, hW1t, hW2t, mW1t, u0t, v1t,
                                        feat, emb, e);

  // 2. concatenated first layer: e -> {Y0, M0}  [N=640, K=256]
  gemm_mfma<64><<<dim3(10, B/64), 256, 0, stream>>>(e, catWt, catb, Y0, M0, 128,
      nullptr, nullptr, nullptr, nullptr, S+0, S+640, 640, 256);

  // 3. Y1 [N=64,K=128]; then Y1' + Gram; then closed-form H stats
  gemm_mfma<64><<<dim3(1, B/64), 256, 0, stream>>>(Y0, hW1t, hb1, Y1, nullptr, 0,
      S+0, S+640, hg0, hbe0, S+1280, S+1344, 64, 128);
  gram_kernel<<<256, 256, 0, stream>>>(Y1, S+1280, S+1344, hg1, hbe1, Y1p, gsum, G);
  hstats_kernel<<<4, 256, 0, stream>>>(gsum, G, hW2t, hb2, S+1408, S+2432);

  // 4. MLP second layer: M0 -> Mout  [N=256, K=512]
  gemm_mfma<64><<<dim3(4, B/64), 256, 0, stream>>>(M0, mW1t, mb1, Mout, nullptr, 0,
      S+128, S+768, mg0, mbe0, S+3456, S+3712, 256, 512);

  // 5. adapter (H recomputed in-LDS) -> Z2, then T = Z2 @ v1 + ab1
  adapter_core<<<B/16, 512, 0, stream>>>(Y1p, Mout, u0t, hW2t, hb2, v0, u1, ab0,
      S+1408, S+2432, hg2, hbe2, S+3456, S+3712, mg1, mbe1, Z2);
  gemm_mfma<32><<<dim3(4, B/64), 256, 0, stream>>>(Z2, v1t, ab1, T, nullptr, 0,
      nullptr, nullptr, nullptr, nullptr, S+3968, S+4224, 256, 32);

  // 6. final head
  final_kernel<<<B/4, 256, 0, stream>>>(e, cw, cb, T, Mout,
      S+3968, S+4224, gamma1, bias1,
      S+3456, S+3712, mg1, mbe1, lw, lb, out);
}

// Round 14
// 323.540 us; speedup vs baseline: 1.7294x; 1.7294x over previous
//
#include <hip/hip_runtime.h>

typedef unsigned short u16;
typedef __attribute__((ext_vector_type(8))) short bf16x8;
typedef __attribute__((ext_vector_type(4))) float f32x4;
#define BATCH 16384

__device__ __forceinline__ float b2f(u16 u){ unsigned int i=((unsigned int)u)<<16; float f; __builtin_memcpy(&f,&i,4); return f; }
__device__ __forceinline__ u16 f2b(float f){ unsigned int x; __builtin_memcpy(&x,&f,4); unsigned int r=(x + 0x7fffu + ((x>>16)&1u))>>16; return (u16)r; }

// ---------------- prep: zero stats + catb + transpose weights + gather ----------------
__global__ __launch_bounds__(256) void prep_kernel(float* __restrict__ S,
                                                   const float* __restrict__ hb0, const float* __restrict__ mb0,
                                                   float* __restrict__ catb,
                                                   const float* __restrict__ w0, const float* __restrict__ w1,
                                                   const float* __restrict__ w2, const float* __restrict__ w3,
                                                   const float* __restrict__ w4, const float* __restrict__ w5,
                                                   const float* __restrict__ w6,
                                                   u16* __restrict__ catWt, u16* __restrict__ t1,
                                                   u16* __restrict__ t2, u16* __restrict__ t4,
                                                   u16* __restrict__ t5, u16* __restrict__ t6,
                                                   const int* __restrict__ ids,
                                                   const float* __restrict__ emb,
                                                   u16* __restrict__ e){
  int blk = blockIdx.x;
  int tid = threadIdx.x;
  if (blk < 18){
    int i = blk*256 + tid;
    if (i < 4480) S[i] = 0.f;
  } else if (blk == 18){
    for (int i = tid; i < 640; i += 256) catb[i] = (i < 128) ? hb0[i] : mb0[i-128];
  } else if (blk < 1523){
    int c = blk - 19;
    if (c < 640){        int idx=c*256+tid;        int n=idx>>8, k=idx&255;
                         catWt[idx] = f2b(n<128 ? w0[k*128+n] : w3[k*512+(n-128)]); }
    else if (c < 672){   int idx=(c-640)*256+tid;  t1[idx]=f2b(w1[(idx%128)*64   + idx/128]); }
    else if (c < 928){   int idx=(c-672)*256+tid;  t2[idx]=f2b(w2[(idx%64)*1024  + idx/64]);  }
    else if (c < 1440){  int idx=(c-928)*256+tid;  t4[idx]=f2b(w4[(idx%512)*256  + idx/512]); }
    else if (c < 1472){  int idx=(c-1440)*256+tid; t5[idx]=f2b(w5[(idx%256)*32   + idx/256]); }
    else {               int idx=(c-1472)*256+tid; t6[idx]=f2b(w6[(idx%32)*256   + idx/32]);  }
  } else {
    int g = blk - 1523;
    int b = g*16 + (tid >> 4), f = tid & 15;
    int id = ids[b*16 + f];
    const float4* src = (const float4*)(emb + ((size_t)f*100000 + (size_t)id)*16);
    float4 v0 = src[0], v1 = src[1], v2 = src[2], v3 = src[3];
    u16 o[16] = { f2b(v0.x),f2b(v0.y),f2b(v0.z),f2b(v0.w), f2b(v1.x),f2b(v1.y),f2b(v1.z),f2b(v1.w),
                  f2b(v2.x),f2b(v2.y),f2b(v2.z),f2b(v2.w), f2b(v3.x),f2b(v3.y),f2b(v3.z),f2b(v3.w) };
    uint4 p0, p1; __builtin_memcpy(&p0, &o[0], 16); __builtin_memcpy(&p1, &o[8], 16);
    uint4* dst = (uint4*)(e + (size_t)b*256 + f*16);
    dst[0] = p0; dst[1] = p1;
  }
}

// ================= 64x64 MFMA GEMM body (device fn), templated BK, reg-prefetch ==========
template<int BK>
__device__ __forceinline__ void gemm_body(const u16* __restrict__ A,
                                          const u16* __restrict__ Wt,
                                          const float* __restrict__ bias,
                                          u16* __restrict__ Ca,
                                          u16* __restrict__ Cb,
                                          int Nsplit,
                                          const float* __restrict__ asums,
                                          const float* __restrict__ asumsq,
                                          const float* __restrict__ ag,
                                          const float* __restrict__ abe,
                                          float* __restrict__ sums,
                                          float* __restrict__ sumsq,
                                          int N, int K, int n0, int m0,
                                          u16* lds, float* bnS, float* bnB){
  constexpr int STR = BK + 8;
  constexpr int EPT = BK/4;
  u16* As = lds;
  u16* Bs = lds + 64*STR;
  int tid = threadIdx.x;
  int lane = tid & 63, w = tid >> 6, quad = lane >> 4, m16 = lane & 15;
  int srow = tid >> 2, skoff = (tid & 3)*EPT;
  if (asums != nullptr){
    for (int k = tid; k < K; k += 256){
      float mean = asums[k] * (1.f/(float)BATCH);
      float var  = asumsq[k] * (1.f/(float)BATCH) - mean*mean;
      float sc   = ag[k] * rsqrtf(var + 1e-5f);
      bnS[k] = sc;
      bnB[k] = abe[k] - mean*sc;
    }
    __syncthreads();
  }
  f32x4 acc[4] = {};
  int ng = n0 + srow;
  uint4 a0, a1, b0, b1;
  {
    const u16* ap = A + (size_t)(m0+srow)*K + skoff;
    a0 = *(const uint4*)ap;
    if (EPT == 16) a1 = *(const uint4*)(ap + 8);
    if (ng < N){
      const u16* bp = Wt + (size_t)ng*K + skoff;
      b0 = *(const uint4*)bp;
      if (EPT == 16) b1 = *(const uint4*)(bp + 8);
    } else { b0 = make_uint4(0u,0u,0u,0u); b1 = b0; }
  }
  for (int k0 = 0; k0 < K; k0 += BK){
    u16 at[EPT];
    __builtin_memcpy(at, &a0, 16);
    if (EPT == 16) __builtin_memcpy(at+8, &a1, 16);
    if (asums != nullptr){
#pragma unroll
      for (int j=0;j<EPT;j++){
        float v = b2f(at[j]) * bnS[k0+skoff+j] + bnB[k0+skoff+j];
        at[j] = f2b(v > 0.f ? v : 0.f);
      }
    }
    uint4 s0, s1;
    __builtin_memcpy(&s0, at, 16);
    *(uint4*)&As[srow*STR + skoff] = s0;
    if (EPT == 16){ __builtin_memcpy(&s1, at+8, 16); *(uint4*)&As[srow*STR + skoff + 8] = s1; }
    *(uint4*)&Bs[srow*STR + skoff] = b0;
    if (EPT == 16) *(uint4*)&Bs[srow*STR + skoff + 8] = b1;
    if (k0 + BK < K){
      const u16* ap = A + (size_t)(m0+srow)*K + k0 + BK + skoff;
      a0 = *(const uint4*)ap;
      if (EPT == 16) a1 = *(const uint4*)(ap + 8);
      if (ng < N){
        const u16* bp = Wt + (size_t)ng*K + k0 + BK + skoff;
        b0 = *(const uint4*)bp;
        if (EPT == 16) b1 = *(const uint4*)(bp + 8);
      }
    }
    __syncthreads();
#pragma unroll
    for (int sub=0; sub<BK/32; sub++){
      bf16x8 bfrag = *(bf16x8*)&Bs[(w*16 + m16)*STR + sub*32 + quad*8];
#pragma unroll
      for (int mc=0;mc<4;mc++){
        bf16x8 afrag = *(bf16x8*)&As[(mc*16 + m16)*STR + sub*32 + quad*8];
        acc[mc] = __builtin_amdgcn_mfma_f32_16x16x32_bf16(afrag, bfrag, acc[mc], 0, 0, 0);
      }
    }
    __syncthreads();
  }
  int cw = n0 + w*16 + m16;
  float bvv = (bias != nullptr && cw < N) ? bias[cw] : 0.f;
  float cs = 0.f, cq = 0.f;
  u16* Cs = lds;
#pragma unroll
  for (int mc=0;mc<4;mc++)
#pragma unroll
    for (int r=0;r<4;r++){
      float v = acc[mc][r] + bvv;
      cs += v; cq += v*v;
      Cs[(mc*16 + quad*4 + r)*72 + w*16 + m16] = f2b(v);
    }
  if (sums != nullptr){
    cs += __shfl_xor(cs, 16, 64); cs += __shfl_xor(cs, 32, 64);
    cq += __shfl_xor(cq, 16, 64); cq += __shfl_xor(cq, 32, 64);
    if (quad == 0 && cw < N){ atomicAdd(&sums[cw], cs); atomicAdd(&sumsq[cw], cq); }
  }
  __syncthreads();
  int row = tid >> 2, c4 = (tid & 3)*16;
  int cg = n0 + c4;
  if (cg < N){
    u16* outp; int stride, colbase;
    if (Cb != nullptr && n0 >= Nsplit){ outp = Cb; stride = N - Nsplit; colbase = cg - Nsplit; }
    else if (Cb != nullptr){            outp = Ca; stride = Nsplit;     colbase = cg; }
    else {                              outp = Ca; stride = N;          colbase = cg; }
    uint4 p0 = *(uint4*)&Cs[row*72 + c4];
    uint4 p1 = *(uint4*)&Cs[row*72 + c4 + 8];
    *(uint4*)(outp + (size_t)(m0+row)*stride + colbase) = p0;
    *(uint4*)(outp + (size_t)(m0+row)*stride + colbase + 8) = p1;
  }
}

template<int BK>
__global__ __launch_bounds__(256) void gemm_mfma(const u16* __restrict__ A,
                                                 const u16* __restrict__ Wt,
                                                 const float* __restrict__ bias,
                                                 u16* __restrict__ Ca,
                                                 u16* __restrict__ Cb,
                                                 int Nsplit,
                                                 const float* __restrict__ asums,
                                                 const float* __restrict__ asumsq,
                                                 const float* __restrict__ ag,
                                                 const float* __restrict__ abe,
                                                 float* __restrict__ sums,
                                                 float* __restrict__ sumsq,
                                                 int N, int K){
  constexpr int STR = BK + 8;
  __shared__ u16 lds[64*STR*2];
  __shared__ float bnS[512], bnB[512];
  gemm_body<BK>(A, Wt, bias, Ca, Cb, Nsplit, asums, asumsq, ag, abe,
                sums, sumsq, N, K, blockIdx.x*64, blockIdx.y*64, lds, bnS, bnB);
}

// Fused launch for two independent GEMMs (Y1 and Mout) — block-uniform branch.
__global__ __launch_bounds__(256) void gemm_dual(
    const u16* __restrict__ A1, const u16* __restrict__ Wt1, const float* __restrict__ b1,
    u16* __restrict__ C1,
    const float* __restrict__ as1, const float* __restrict__ aq1,
    const float* __restrict__ g1v, const float* __restrict__ be1,
    float* __restrict__ s1, float* __restrict__ q1, int N1, int K1, int nb1, int nblk1,
    const u16* __restrict__ A2, const u16* __restrict__ Wt2, const float* __restrict__ b2,
    u16* __restrict__ C2,
    const float* __restrict__ as2, const float* __restrict__ aq2,
    const float* __restrict__ g2v, const float* __restrict__ be2,
    float* __restrict__ s2, float* __restrict__ q2, int N2, int K2, int nblk2){
  constexpr int STR = 64 + 8;
  __shared__ u16 lds[64*STR*2];
  __shared__ float bnS[512], bnB[512];
  int blk = blockIdx.x;
  if (blk < nb1){
    int n0 = (blk % nblk1)*64, m0 = (blk / nblk1)*64;
    gemm_body<64>(A1, Wt1, b1, C1, nullptr, 0, as1, aq1, g1v, be1,
                  s1, q1, N1, K1, n0, m0, lds, bnS, bnB);
  } else {
    int q = blk - nb1;
    int n0 = (q % nblk2)*64, m0 = (q / nblk2)*64;
    gemm_body<64>(A2, Wt2, b2, C2, nullptr, 0, as2, aq2, g2v, be2,
                  s2, q2, N2, K2, n0, m0, lds, bnS, bnB);
  }
}

// ---------------- adapter core: 16 rows/block, 512 threads, slim LDS (3 blocks/CU) -------
// Phase order: tables+stage aS -> activate aS -> P (aS + u0t from L2) -> stage Hs
// (OVERWRITES aS region) -> q -> t1 -> s -> z2. PT/QS buffers ping-pong.
#define HSTR 1056
__global__ __launch_bounds__(512) void adapter_core(const u16* __restrict__ H,
                                                    const u16* __restrict__ Mout,
                                                    const u16* __restrict__ u0t,
                                                    const float* __restrict__ v0,
                                                    const float* __restrict__ u1,
                                                    const float* __restrict__ ab0,
                                                    const float* __restrict__ hsums,
                                                    const float* __restrict__ hsumsq,
                                                    const float* __restrict__ hg,
                                                    const float* __restrict__ hbe,
                                                    const float* __restrict__ msums,
                                                    const float* __restrict__ msumsq,
                                                    const float* __restrict__ mg,
                                                    const float* __restrict__ mbe,
                                                    u16* __restrict__ Z2){
  __shared__ __align__(16) u16 Hs[16*HSTR];      // 33 KB; first 4096 u16 alias aS
  __shared__ float bnS[1024], bnB[1024];         // 8 KB
  __shared__ __align__(8) u16 v0s[1024], u1s[1024];  // 4 KB
  __shared__ float mS[256], mB[256];             // 2 KB
  __shared__ float PT[512], QS[512];             // 4 KB (Ps->t1s, qs->ss)
  __shared__ float ab0s[32];
  int tid = threadIdx.x;
  int r = tid >> 5, j = tid & 31;
  size_t row0 = (size_t)blockIdx.x * 16;
  u16* aS = Hs;   // alias: aS dead before Hs staged

  // phase A: tables + stage raw Mout
  for (int k = tid; k < 1024; k += 512){
    float mean = hsums[k] * (1.f/(float)BATCH);
    float var  = hsumsq[k] * (1.f/(float)BATCH) - mean*mean;
    float sc   = hg[k] * rsqrtf(var + 1e-5f);
    bnS[k] = sc; bnB[k] = hbe[k] - mean*sc;
  }
  if (tid < 256){
    float4 a = *(const float4*)(v0 + tid*4);
    ushort4 pa = { f2b(a.x), f2b(a.y), f2b(a.z), f2b(a.w) };
    *(ushort4*)&v0s[tid*4] = pa;
    float4 b4 = *(const float4*)(u1 + tid*4);
    ushort4 pb = { f2b(b4.x), f2b(b4.y), f2b(b4.z), f2b(b4.w) };
    *(ushort4*)&u1s[tid*4] = pb;
  } else {
    int c = tid - 256;
    float mean = msums[c] * (1.f/(float)BATCH);
    float var  = msumsq[c] * (1.f/(float)BATCH) - mean*mean;
    float sc   = mg[c] * rsqrtf(var + 1e-5f);
    mS[c] = sc; mB[c] = mbe[c] - mean*sc;
  }
  {
    int el = tid*8;
    uint4 mv = *(const uint4*)(Mout + row0*256 + el);
    *(uint4*)&aS[el] = mv;
  }
  if (tid < 32) ab0s[tid] = ab0[tid];
  __syncthreads();

  // phase B: activate aS in place
  {
    int el = tid*8, col = el & 255;
    u16 mt[8]; __builtin_memcpy(mt, &aS[el], 16);
#pragma unroll
    for (int q=0;q<8;q++){
      float v = b2f(mt[q]) * mS[col+q] + mB[col+q];
      mt[q] = f2b(v > 0.f ? v : 0.f);
    }
    uint4 so; __builtin_memcpy(&so, mt, 16);
    *(uint4*)&aS[el] = so;
  }
  __syncthreads();

  // phase C: P[r][j] = sum_k aS[r][k] * u0t[j][k]  (u0t from L2)
  {
    float acc = 0.f;
    for (int k8 = 0; k8 < 256; k8 += 8){
      uint4 vu = *(const uint4*)(u0t + j*256 + k8);
      uint4 va; __builtin_memcpy(&va, &aS[r*256 + k8], 16);
      u16 ta[8], tu[8]; __builtin_memcpy(ta, &va, 16); __builtin_memcpy(tu, &vu, 16);
#pragma unroll
      for (int q=0;q<8;q++) acc += b2f(ta[q]) * b2f(tu[q]);
    }
    PT[tid] = acc;
  }
  __syncthreads();                 // P visible; aS dead

  // phase D: Hs = relu(bn(H)) — overwrites aS region
#pragma unroll
  for (int it=0; it<4; it++){
    int el = it*4096 + tid*8;
    int rr = el >> 10, col = el & 1023;
    uint4 hv = *(const uint4*)(H + row0*1024 + el);
    u16 ht[8]; __builtin_memcpy(ht, &hv, 16);
#pragma unroll
    for (int q=0;q<8;q++){
      float v = b2f(ht[q]) * bnS[col+q] + bnB[col+q];
      ht[q] = f2b(v > 0.f ? v : 0.f);
    }
    uint4 so; __builtin_memcpy(&so, ht, 16);
    *(uint4*)&Hs[rr*HSTR + col] = so;
  }
  __syncthreads();

  // q[j] = sum_i P[i] H[i,j]
  float acc = 0.f;
#pragma unroll
  for (int i=0;i<32;i++) acc += PT[r*32+i] * b2f(Hs[r*HSTR + i*32 + j]);
  QS[tid] = acc;
  __syncthreads();
  // t1 = sigmoid(q @ v0 + ab0)   (writes PT)
  acc = ab0s[j];
#pragma unroll
  for (int i=0;i<32;i++) acc += QS[r*32+i] * b2f(v0s[i*32+j]);
  PT[tid] = 1.f / (1.f + __expf(-acc));
  __syncthreads();
  // s = t1 @ u1                  (writes QS)
  acc = 0.f;
#pragma unroll
  for (int i=0;i<32;i++) acc += PT[r*32+i] * b2f(u1s[i*32+j]);
  QS[tid] = acc;
  __syncthreads();
  // z2[j] = sum_i s[i] H[i,j]
  acc = 0.f;
#pragma unroll
  for (int i=0;i<32;i++) acc += QS[r*32+i] * b2f(Hs[r*HSTR + i*32 + j]);
  Z2[(row0 + r)*32 + j] = f2b(acc);
}

// ---------------- final head ----------------
__global__ __launch_bounds__(256) void final_kernel(const u16* __restrict__ e,
                                                    const float* __restrict__ cw,
                                                    const float* __restrict__ cb,
                                                    const u16* __restrict__ t,
                                                    const u16* __restrict__ mo,
                                                    const float* __restrict__ tsums,
                                                    const float* __restrict__ tsumsq,
                                                    const float* __restrict__ tg,
                                                    const float* __restrict__ tbe,
                                                    const float* __restrict__ msums,
                                                    const float* __restrict__ msumsq,
                                                    const float* __restrict__ mg,
                                                    const float* __restrict__ mbe,
                                                    const float* __restrict__ lw,
                                                    const float* __restrict__ lb,
                                                    float* __restrict__ out){
  __shared__ float tS[256], tB[256], mS[256], mB[256];
  int tid = threadIdx.x;
  {
    int c = tid;
    float mean = tsums[c] * (1.f/(float)BATCH);
    float var  = (tsumsq[c] - mean*mean*(float)BATCH) * (1.f/(float)(BATCH-1));
    float sc   = tg[c] * rsqrtf(var + 1e-5f);
    tS[c] = sc; tB[c] = tbe[c] - mean*sc;
    float mmean = msums[c] * (1.f/(float)BATCH);
    float mvar  = msumsq[c] * (1.f/(float)BATCH) - mmean*mmean;
    float msc   = mg[c] * rsqrtf(mvar + 1e-5f);
    mS[c] = msc; mB[c] = mbe[c] - mmean*msc;
  }
  __syncthreads();
  int wave = tid >> 6, lane = tid & 63;
  int b = blockIdx.x*4 + wave;
  int n4 = lane*4;
  ushort4 ev = *(const ushort4*)(e + (size_t)b*256 + n4);
  float ec[4] = { b2f(ev.x), b2f(ev.y), b2f(ev.z), b2f(ev.w) };
  float x[4]  = { ec[0], ec[1], ec[2], ec[3] };
  for (int i=0;i<3;i++){
    float p = 0.f;
#pragma unroll
    for (int q=0;q<4;q++) p += x[q] * cw[i*256 + n4 + q];
#pragma unroll
    for (int o=1;o<64;o<<=1) p += __shfl_xor(p, o, 64);
#pragma unroll
    for (int q=0;q<4;q++) x[q] = ec[q]*p + cb[i*256 + n4 + q] + x[q];
  }
  ushort4 tv = *(const ushort4*)(t  + (size_t)b*256 + n4);
  ushort4 mv = *(const ushort4*)(mo + (size_t)b*256 + n4);
  float ta[4] = { b2f(tv.x), b2f(tv.y), b2f(tv.z), b2f(tv.w) };
  float ma[4] = { b2f(mv.x), b2f(mv.y), b2f(mv.z), b2f(mv.w) };
  float p = 0.f;
#pragma unroll
  for (int q=0;q<4;q++){
    int n = n4 + q;
    p += x[q] * lw[n];
    float mr = ma[q]*mS[n] + mB[n];
    mr = mr > 0.f ? mr : 0.f;
    float mf = tS[n]*ta[q] + tB[n] + mr;
    p += mf * lw[256 + n];
  }
#pragma unroll
  for (int o=32;o>0;o>>=1) p += __shfl_down(p, o, 64);
  if (lane == 0){
    float y = p + lb[0];
    out[b] = 1.f / (1.f + __expf(-y));
  }
}

extern "C" void kernel_launch(void* const* d_in, const int* in_sizes, int n_in,
                              void* d_out, int out_size, void* d_ws, size_t ws_size,
                              hipStream_t stream) {
  const int B = BATCH;
  const int*   feat = (const int*)d_in[0];
  const float* emb  = (const float*)d_in[2];
  const float* hW0 = (const float*)d_in[3],  *hb0 = (const float*)d_in[4],  *hg0 = (const float*)d_in[5],  *hbe0 = (const float*)d_in[6];
  const float* hW1 = (const float*)d_in[7],  *hb1 = (const float*)d_in[8],  *hg1 = (const float*)d_in[9],  *hbe1 = (const float*)d_in[10];
  const float* hW2 = (const float*)d_in[11], *hb2 = (const float*)d_in[12], *hg2 = (const float*)d_in[13], *hbe2 = (const float*)d_in[14];
  const float* cw  = (const float*)d_in[15], *cb  = (const float*)d_in[16];
  const float* mW0 = (const float*)d_in[17], *mb0 = (const float*)d_in[18], *mg0 = (const float*)d_in[19], *mbe0 = (const float*)d_in[20];
  const float* mW1 = (const float*)d_in[21], *mb1 = (const float*)d_in[22], *mg1 = (const float*)d_in[23], *mbe1 = (const float*)d_in[24];
  const float* u0  = (const float*)d_in[25], *u1  = (const float*)d_in[26];
  const float* v0  = (const float*)d_in[27], *v1  = (const float*)d_in[28];
  const float* ab0 = (const float*)d_in[29], *ab1 = (const float*)d_in[30];
  const float* gamma1 = (const float*)d_in[31], *bias1 = (const float*)d_in[32];
  const float* lw  = (const float*)d_in[33], *lb = (const float*)d_in[34];
  float* out = (float*)d_out;

  // ---- disjoint workspace layout (~89 MB) ----
  char* base = (char*)d_ws;
  const size_t MB = 1024*1024;
  u16* H    = (u16*)(base);             // [B,1024]  32 MB
  u16* e    = (u16*)(base + 32*MB);     // [B,256]
  u16* Y0   = (u16*)(base + 40*MB);     // [B,128]
  u16* Y1   = (u16*)(base + 44*MB);     // [B,64]
  u16* M0   = (u16*)(base + 48*MB);     // [B,512]
  u16* Mout = (u16*)(base + 64*MB);     // [B,256]
  u16* T    = (u16*)(base + 72*MB);     // [B,256]
  u16* Z2   = (u16*)(base + 80*MB);     // [B,32]
  u16* catWt= (u16*)(base + 88*MB);     // [640][256]
  u16* hW1t = catWt + 163840;           // [64][128]
  u16* hW2t = hW1t + 8192;              // [1024][64]
  u16* mW1t = hW2t + 65536;             // [256][512]
  u16* u0t  = mW1t + 131072;            // [32][256]
  u16* v1t  = u0t + 8192;               // [256][32]
  float* catb = (float*)(v1t + 8192);   // [640]
  float* S    = catb + 640;             // 4480 floats of stats

  // 1. prep
  prep_kernel<<<2547, 256, 0, stream>>>(S, hb0, mb0, catb,
                                        hW0, hW1, hW2, mW0, mW1, u0, v1,
                                        catWt, hW1t, hW2t, mW1t, u0t, v1t,
                                        feat, emb, e);

  // 2. concatenated first layer: e -> {Y0 (cols<128), M0 (cols>=128)}  [N=640, K=256]
  gemm_mfma<64><<<dim3(10, B/64), 256, 0, stream>>>(e, catWt, catb, Y0, M0, 128,
      nullptr, nullptr, nullptr, nullptr, S+0, S+640, 640, 256);

  // 3. fused dual GEMM: Y1 [N=64,K=128, 256 blocks] + Mout [N=256,K=512, 1024 blocks]
  gemm_dual<<<1280, 256, 0, stream>>>(
      Y0, hW1t, hb1, Y1, S+0, S+640, hg0, hbe0, S+1280, S+1344, 64, 128, 256, 1,
      M0, mW1t, mb1, Mout, S+128, S+768, mg0, mbe0, S+3456, S+3712, 256, 512, 4);

  // 4. H [N=1024, K=64]
  gemm_mfma<64><<<dim3(16, B/64), 256, 0, stream>>>(Y1, hW2t, hb2, H, nullptr, 0,
      S+1280, S+1344, hg1, hbe1, S+1408, S+2432, 1024, 64);

  // 5. adapter -> Z2, then T = Z2 @ v1 + ab1  [N=256, K=32]
  adapter_core<<<B/16, 512, 0, stream>>>(H, Mout, u0t, v0, u1, ab0,
      S+1408, S+2432, hg2, hbe2, S+3456, S+3712, mg1, mbe1, Z2);
  gemm_mfma<32><<<dim3(4, B/64), 256, 0, stream>>>(Z2, v1t, ab1, T, nullptr, 0,
      nullptr, nullptr, nullptr, nullptr, S+3968, S+4224, 256, 32);

  // 6. final head
  final_kernel<<<B/4, 256, 0, stream>>>(e, cw, cb, T, Mout,
      S+3968, S+4224, gamma1, bias1,
      S+3456, S+3712, mg1, mbe1, lw, lb, out);
}